// Round 1
// baseline (294.308 us; speedup 1.0000x reference)
//
#include <hip/hip_runtime.h>

typedef __bf16 bf16;
typedef __bf16 bf16x8 __attribute__((ext_vector_type(8)));
typedef float floatx4 __attribute__((ext_vector_type(4)));

#define IN_F  1024
#define OUT_F 4096
#define M_DIM 8192   // 16*512
#define K_DIM 1024
#define N_DIM 4096

__device__ __forceinline__ unsigned short f2bf(float f) {
    unsigned int u = __float_as_uint(f);
    u += 0x7FFFu + ((u >> 16) & 1u);   // round-to-nearest-even
    return (unsigned short)(u >> 16);
}

// ---------------------------------------------------------------------------
// Kernel 1: build effective weight W' (bf16, row-major [OUT_F][IN_F] = B^T)
// W'[o,i] = a0*W[o,i] + sum_{bs in 2,4,8,16} a_bs * (1/bs) *
//           sum_r W[ob+r][ib + ((r + (o-i)) mod bs)]
// ---------------------------------------------------------------------------
__global__ __launch_bounds__(256) void build_w_kernel(
    const float* __restrict__ W, const float* __restrict__ alphas,
    unsigned short* __restrict__ Wb)
{
    const int idx = blockIdx.x * 256 + threadIdx.x;
    const int o = idx >> 10;        // / IN_F
    const int i = idx & 1023;

    // softmax over 5 alphas (tiny, recomputed per thread; scalar-cached loads)
    float av[5];
    float mx = -1e30f;
    #pragma unroll
    for (int j = 0; j < 5; ++j) { av[j] = alphas[j]; mx = fmaxf(mx, av[j]); }
    float s = 0.f;
    #pragma unroll
    for (int j = 0; j < 5; ++j) { av[j] = __expf(av[j] - mx); s += av[j]; }
    const float inv = 1.f / s;
    #pragma unroll
    for (int j = 0; j < 5; ++j) av[j] *= inv;

    float acc = av[0] * W[(size_t)o * IN_F + i];

    #pragma unroll
    for (int e = 1; e <= 4; ++e) {
        const int bs   = 1 << e;
        const int mask = bs - 1;
        const int ob = o & ~mask;
        const int ib = i & ~mask;
        const int d  = (o - i) & mask;
        float ssum = 0.f;
        #pragma unroll
        for (int r = 0; r < bs; ++r) {
            const int col = ib + ((r + d) & mask);
            ssum += W[(size_t)(ob + r) * IN_F + col];
        }
        acc += av[e] * (1.0f / (float)bs) * ssum;
    }
    Wb[idx] = f2bf(acc);
}

// ---------------------------------------------------------------------------
// Kernel 2: x f32 -> bf16, 8 elements/thread
// ---------------------------------------------------------------------------
__global__ __launch_bounds__(256) void cvt_x_kernel(
    const float* __restrict__ x, uint4* __restrict__ xb)
{
    const int t = blockIdx.x * 256 + threadIdx.x;
    const float4* xv = (const float4*)x;
    const float4 v0 = xv[2 * t];
    const float4 v1 = xv[2 * t + 1];
    uint4 o;
    o.x = (unsigned)f2bf(v0.x) | ((unsigned)f2bf(v0.y) << 16);
    o.y = (unsigned)f2bf(v0.z) | ((unsigned)f2bf(v0.w) << 16);
    o.z = (unsigned)f2bf(v1.x) | ((unsigned)f2bf(v1.y) << 16);
    o.w = (unsigned)f2bf(v1.z) | ((unsigned)f2bf(v1.w) << 16);
    xb[t] = o;
}

// ---------------------------------------------------------------------------
// Kernel 3: C[M][N] = A[M][K] * B[N][K]^T + bias    (m97-style MFMA GEMM)
// 128x128 tile, BK=64, 256 threads (4 waves, 2x2 of 64x64), 16x16x32 bf16 MFMA
// ---------------------------------------------------------------------------
__global__ __launch_bounds__(256) void gemm_bt_kernel(
    const bf16* __restrict__ A, const bf16* __restrict__ B,
    const float* __restrict__ bias, float* __restrict__ C)
{
    constexpr int M = M_DIM, N = N_DIM, K = K_DIM;
    constexpr int TM = 128, TN = 128, TK = 64;
    (void)M;

    __shared__ __align__(16) bf16 As[TM * TK];
    __shared__ __align__(16) bf16 Bs[TN * TK];

    const int t    = threadIdx.x;
    const int w    = t >> 6;
    const int l    = t & 63;
    const int quad = l >> 4;
    const int l16  = l & 15;

    const int nb = N / TN;                 // 32
    const int bm = blockIdx.x / nb;
    const int bn = blockIdx.x % nb;

    const int wm = (w >> 1) * 64;
    const int wn = (w & 1) * 64;

    floatx4 acc[4][4] = {};

    // staging layout: 16B chunk c (0..1023) -> LDS byte c*16;
    // row = c>>3, col(bf16) = (c&7)*8. Per q, wave-uniform LDS base + lane*16.
    int crow[4], ccol[4], loff[4];
    #pragma unroll
    for (int q = 0; q < 4; ++q) {
        const int chunk = q * 256 + t;
        crow[q] = chunk >> 3;
        ccol[q] = (chunk & 7) * 8;
        loff[q] = (q * 256 + (t & ~63)) * 8;   // elements; uniform per wave
    }

    const bf16* Abase = A + (size_t)bm * TM * K;
    const bf16* Bbase = B + (size_t)bn * TN * K;

    for (int kt = 0; kt < K; kt += TK) {
        #pragma unroll
        for (int q = 0; q < 4; ++q) {
            __builtin_amdgcn_global_load_lds(
                (const __attribute__((address_space(1))) void*)(Abase + (size_t)crow[q] * K + kt + ccol[q]),
                (__attribute__((address_space(3))) void*)(As + loff[q]), 16, 0, 0);
        }
        #pragma unroll
        for (int q = 0; q < 4; ++q) {
            __builtin_amdgcn_global_load_lds(
                (const __attribute__((address_space(1))) void*)(Bbase + (size_t)crow[q] * K + kt + ccol[q]),
                (__attribute__((address_space(3))) void*)(Bs + loff[q]), 16, 0, 0);
        }
        __syncthreads();

        #pragma unroll
        for (int ks = 0; ks < 2; ++ks) {
            bf16x8 af[4], bfr[4];
            #pragma unroll
            for (int mt = 0; mt < 4; ++mt)
                af[mt] = *(const bf16x8*)(As + (wm + mt * 16 + l16) * TK + ks * 32 + quad * 8);
            #pragma unroll
            for (int nt = 0; nt < 4; ++nt)
                bfr[nt] = *(const bf16x8*)(Bs + (wn + nt * 16 + l16) * TK + ks * 32 + quad * 8);
            #pragma unroll
            for (int mt = 0; mt < 4; ++mt)
                #pragma unroll
                for (int nt = 0; nt < 4; ++nt)
                    acc[mt][nt] = __builtin_amdgcn_mfma_f32_16x16x32_bf16(
                        af[mt], bfr[nt], acc[mt][nt], 0, 0, 0);
        }
        __syncthreads();
    }

    // epilogue: C/D layout col = lane&15, row = quad*4 + reg  (m89-verified)
    float bv[4];
    #pragma unroll
    for (int nt = 0; nt < 4; ++nt)
        bv[nt] = bias[bn * TN + wn + nt * 16 + l16];

    float* Cbase = C + (size_t)(bm * TM + wm) * N + bn * TN + wn;
    #pragma unroll
    for (int mt = 0; mt < 4; ++mt) {
        #pragma unroll
        for (int r = 0; r < 4; ++r) {
            float* crowp = Cbase + (size_t)(mt * 16 + quad * 4 + r) * N;
            #pragma unroll
            for (int nt = 0; nt < 4; ++nt)
                crowp[nt * 16 + l16] = acc[mt][nt][r] + bv[nt];
        }
    }
}

// ---------------------------------------------------------------------------
extern "C" void kernel_launch(void* const* d_in, const int* in_sizes, int n_in,
                              void* d_out, int out_size, void* d_ws, size_t ws_size,
                              hipStream_t stream) {
    const float* x      = (const float*)d_in[0];   // [16,512,1024]
    const float* weight = (const float*)d_in[1];   // [4096,1024]
    const float* alphas = (const float*)d_in[2];   // [5]
    const float* bias   = (const float*)d_in[3];   // [4096]
    float* out = (float*)d_out;                    // [16,512,4096] f32

    // workspace: Wb (bf16, 8 MB) | Xb (bf16, 16 MB)
    unsigned short* Wb = (unsigned short*)d_ws;
    unsigned short* Xb = (unsigned short*)((char*)d_ws + (size_t)OUT_F * IN_F * 2);

    build_w_kernel<<<(OUT_F * IN_F) / 256, 256, 0, stream>>>(weight, alphas, Wb);
    cvt_x_kernel<<<(M_DIM * K_DIM / 8) / 256, 256, 0, stream>>>(x, (uint4*)Xb);

    const int grid = (M_DIM / 128) * (N_DIM / 128);   // 64*32 = 2048 blocks
    gemm_bt_kernel<<<grid, 256, 0, stream>>>((const bf16*)Xb, (const bf16*)Wb, bias, out);
}

// Round 2
// 249.963 us; speedup vs baseline: 1.1774x; 1.1774x over previous
//
#include <hip/hip_runtime.h>

typedef __bf16 bf16;
typedef __bf16 bf16x8 __attribute__((ext_vector_type(8)));
typedef float floatx4 __attribute__((ext_vector_type(4)));

#define IN_F  1024
#define OUT_F 4096
#define M_DIM 8192   // 16*512
#define K_DIM 1024
#define N_DIM 4096

__device__ __forceinline__ unsigned short f2bf(float f) {
    unsigned int u = __float_as_uint(f);
    u += 0x7FFFu + ((u >> 16) & 1u);   // round-to-nearest-even
    return (unsigned short)(u >> 16);
}

// ---------------------------------------------------------------------------
// Kernel 1: build effective weight W' (bf16, row-major [OUT_F][IN_F] = B^T)
// W'[o,i] = a0*W[o,i] + sum_{bs in 2,4,8,16} a_bs * (1/bs) *
//           sum_r W[ob+r][ib + ((r + (o-i)) mod bs)]
// LDS-staged: block = 16 rows x 256 cols strip; all diagonal sums read LDS.
// Lane mapping: jj = t&15 varies diagonal index d -> every LDS read
// instruction touches 16 distinct columns -> conflict-free.
// ---------------------------------------------------------------------------
__global__ __launch_bounds__(256) void build_w_kernel(
    const float* __restrict__ W, const float* __restrict__ alphas,
    unsigned short* __restrict__ Wb)
{
    __shared__ float Wl[16 * 256];   // 16 KB

    const int t = threadIdx.x;
    const int rb = blockIdx.x >> 2;      // 256 row-blocks
    const int cb = blockIdx.x & 3;       // 4 col-blocks
    const int row0 = rb * 16, col0 = cb * 256;

    // --- load strip (float4, coalesced) ---
    const float4* src = (const float4*)(W + (size_t)row0 * IN_F + col0);
    #pragma unroll
    for (int j = 0; j < 4; ++j) {
        const int idx = j * 256 + t;          // 0..1023 float4s
        const int r = idx >> 6, c4 = idx & 63;
        ((float4*)Wl)[r * 64 + c4] = src[(size_t)r * 256 + c4];
    }

    // --- softmax over 5 alphas (cheap, per-thread) ---
    float av[5];
    float mx = -1e30f;
    #pragma unroll
    for (int j = 0; j < 5; ++j) { av[j] = alphas[j]; mx = fmaxf(mx, av[j]); }
    float s = 0.f;
    #pragma unroll
    for (int j = 0; j < 5; ++j) { av[j] = __expf(av[j] - mx); s += av[j]; }
    const float inv = 1.f / s;
    #pragma unroll
    for (int j = 0; j < 5; ++j) av[j] *= inv;

    __syncthreads();

    // --- compute: thread t -> row k = t>>4, cols j = jj + 16*jb, jj = t&15 ---
    const int k  = t >> 4;
    const int jj = t & 15;
    unsigned short ov[16];

    #pragma unroll
    for (int jb = 0; jb < 16; ++jb) {
        const int j = jb * 16 + jj;
        float acc = av[0] * Wl[k * 256 + j];
        #pragma unroll
        for (int e = 1; e <= 4; ++e) {
            const int bs   = 1 << e;
            const int mask = bs - 1;
            const int ol = k & ~mask;
            const int il = j & ~mask;
            const int d  = (k - j) & mask;
            float ssum = 0.f;
            #pragma unroll
            for (int r = 0; r < bs; ++r)
                ssum += Wl[(ol + r) * 256 + il + ((r + d) & mask)];
            acc += av[e] * (1.0f / (float)bs) * ssum;
        }
        ov[jb] = f2bf(acc);
    }

    // --- repack through LDS for vectorized global stores ---
    __syncthreads();
    unsigned short* Wls = (unsigned short*)Wl;
    #pragma unroll
    for (int jb = 0; jb < 16; ++jb)
        Wls[k * 256 + jb * 16 + jj] = ov[jb];
    __syncthreads();

    const int kr = t >> 4, cg = t & 15;
    const uint4* p = (const uint4*)(Wls + kr * 256 + cg * 16);
    uint4* dst = (uint4*)(Wb + (size_t)(row0 + kr) * IN_F + col0 + cg * 16);
    dst[0] = p[0];
    dst[1] = p[1];
}

// ---------------------------------------------------------------------------
// Kernel 2: x f32 -> bf16, 8 elements/thread
// ---------------------------------------------------------------------------
__global__ __launch_bounds__(256) void cvt_x_kernel(
    const float* __restrict__ x, uint4* __restrict__ xb)
{
    const int t = blockIdx.x * 256 + threadIdx.x;
    const float4* xv = (const float4*)x;
    const float4 v0 = xv[2 * t];
    const float4 v1 = xv[2 * t + 1];
    uint4 o;
    o.x = (unsigned)f2bf(v0.x) | ((unsigned)f2bf(v0.y) << 16);
    o.y = (unsigned)f2bf(v0.z) | ((unsigned)f2bf(v0.w) << 16);
    o.z = (unsigned)f2bf(v1.x) | ((unsigned)f2bf(v1.y) << 16);
    o.w = (unsigned)f2bf(v1.z) | ((unsigned)f2bf(v1.w) << 16);
    xb[t] = o;
}

// ---------------------------------------------------------------------------
// Kernel 3: C[M][N] = A[M][K] * B[N][K]^T + bias    (MFMA GEMM, XOR-swizzled LDS)
// 128x128 tile, BK=64, 256 threads (4 waves, 2x2 of 64x64), 16x16x32 bf16 MFMA.
// LDS 16B-slot (row, s) holds logical K-chunk  kc = s ^ (row & 7): staging
// permutes SOURCE addresses (global_load_lds placement is forced to be
// lane-contiguous), fragment reads become bank-conflict-free.
// ---------------------------------------------------------------------------
__global__ __launch_bounds__(256) void gemm_bt_kernel(
    const bf16* __restrict__ A, const bf16* __restrict__ B,
    const float* __restrict__ bias, float* __restrict__ C)
{
    constexpr int N = N_DIM, K = K_DIM;
    constexpr int TM = 128, TN = 128, TK = 64;

    __shared__ __align__(16) bf16 As[TM * TK];
    __shared__ __align__(16) bf16 Bs[TN * TK];

    const int t    = threadIdx.x;
    const int w    = t >> 6;
    const int l    = t & 63;
    const int quad = l >> 4;
    const int l16  = l & 15;
    const int x7   = l16 & 7;

    const int nb = N / TN;                 // 32
    const int bm = blockIdx.x / nb;
    const int bn = blockIdx.x % nb;

    const int wm = (w >> 1) * 64;
    const int wn = (w & 1) * 64;

    floatx4 acc[4][4] = {};

    // staging: LDS slot 'chunk' (lane-ordered, forced) holds global chunk
    // (row = chunk>>3, kc = (chunk&7) ^ (row&7))
    int crow[4], ccol[4], loff[4];
    #pragma unroll
    for (int q = 0; q < 4; ++q) {
        const int chunk = q * 256 + t;
        crow[q] = chunk >> 3;
        ccol[q] = (((chunk & 7) ^ ((chunk >> 3) & 7)) * 8);
        loff[q] = (q * 256 + (t & ~63)) * 8;   // elements; uniform per wave
    }

    const bf16* Abase = A + (size_t)bm * TM * K;
    const bf16* Bbase = B + (size_t)bn * TN * K;

    for (int kt = 0; kt < K; kt += TK) {
        #pragma unroll
        for (int q = 0; q < 4; ++q) {
            __builtin_amdgcn_global_load_lds(
                (const __attribute__((address_space(1))) void*)(Abase + (size_t)crow[q] * K + kt + ccol[q]),
                (__attribute__((address_space(3))) void*)(As + loff[q]), 16, 0, 0);
        }
        #pragma unroll
        for (int q = 0; q < 4; ++q) {
            __builtin_amdgcn_global_load_lds(
                (const __attribute__((address_space(1))) void*)(Bbase + (size_t)crow[q] * K + kt + ccol[q]),
                (__attribute__((address_space(3))) void*)(Bs + loff[q]), 16, 0, 0);
        }
        __syncthreads();

        #pragma unroll
        for (int ks = 0; ks < 2; ++ks) {
            bf16x8 af[4], bfr[4];
            const int kx = ((ks * 4 + quad) ^ x7) * 8;   // swizzled K-offset
            #pragma unroll
            for (int mt = 0; mt < 4; ++mt)
                af[mt] = *(const bf16x8*)(As + (wm + mt * 16 + l16) * TK + kx);
            #pragma unroll
            for (int nt = 0; nt < 4; ++nt)
                bfr[nt] = *(const bf16x8*)(Bs + (wn + nt * 16 + l16) * TK + kx);
            #pragma unroll
            for (int mt = 0; mt < 4; ++mt)
                #pragma unroll
                for (int nt = 0; nt < 4; ++nt)
                    acc[mt][nt] = __builtin_amdgcn_mfma_f32_16x16x32_bf16(
                        af[mt], bfr[nt], acc[mt][nt], 0, 0, 0);
        }
        __syncthreads();
    }

    // epilogue: C/D layout col = lane&15, row = quad*4 + reg  (m89-verified)
    float bv[4];
    #pragma unroll
    for (int nt = 0; nt < 4; ++nt)
        bv[nt] = bias[bn * TN + wn + nt * 16 + l16];

    float* Cbase = C + (size_t)(bm * TM + wm) * N + bn * TN + wn;
    #pragma unroll
    for (int mt = 0; mt < 4; ++mt) {
        #pragma unroll
        for (int r = 0; r < 4; ++r) {
            float* crowp = Cbase + (size_t)(mt * 16 + quad * 4 + r) * N;
            #pragma unroll
            for (int nt = 0; nt < 4; ++nt)
                crowp[nt * 16 + l16] = acc[mt][nt][r] + bv[nt];
        }
    }
}

// ---------------------------------------------------------------------------
extern "C" void kernel_launch(void* const* d_in, const int* in_sizes, int n_in,
                              void* d_out, int out_size, void* d_ws, size_t ws_size,
                              hipStream_t stream) {
    const float* x      = (const float*)d_in[0];   // [16,512,1024]
    const float* weight = (const float*)d_in[1];   // [4096,1024]
    const float* alphas = (const float*)d_in[2];   // [5]
    const float* bias   = (const float*)d_in[3];   // [4096]
    float* out = (float*)d_out;                    // [16,512,4096] f32

    // workspace: Wb (bf16, 8 MB) | Xb (bf16, 16 MB)
    unsigned short* Wb = (unsigned short*)d_ws;
    unsigned short* Xb = (unsigned short*)((char*)d_ws + (size_t)OUT_F * IN_F * 2);

    build_w_kernel<<<(OUT_F / 16) * (IN_F / 256), 256, 0, stream>>>(weight, alphas, Wb);
    cvt_x_kernel<<<(M_DIM * K_DIM / 8) / 256, 256, 0, stream>>>(x, (uint4*)Xb);

    const int grid = (M_DIM / 128) * (N_DIM / 128);   // 64*32 = 2048 blocks
    gemm_bt_kernel<<<grid, 256, 0, stream>>>((const bf16*)Xb, (const bf16*)Wb, bias, out);
}